// Round 11
// baseline (96.578 us; speedup 1.0000x reference)
//
#include <hip/hip_runtime.h>

typedef __bf16 bf16x8 __attribute__((ext_vector_type(8)));
typedef __bf16 bf16x4 __attribute__((ext_vector_type(4)));
typedef float f32x4 __attribute__((ext_vector_type(4)));
typedef float f32x16 __attribute__((ext_vector_type(16)));
typedef unsigned int u32;

#define T_LEN 4096

__device__ __forceinline__ f32x4 mfma16(bf16x8 a, bf16x8 b, f32x4 c) {
    return __builtin_amdgcn_mfma_f32_16x16x32_bf16(a, b, c, 0, 0, 0);
}
__device__ __forceinline__ f32x16 mfma32(bf16x8 a, bf16x8 b, f32x16 c) {
    return __builtin_amdgcn_mfma_f32_32x32x16_bf16(a, b, c, 0, 0, 0);
}
__device__ __forceinline__ u32 packbf(float lo, float hi) {
    union { __bf16 e[2]; u32 w; } u;
    u.e[0] = (__bf16)lo; u.e[1] = (__bf16)hi;
    return u.w;
}
__device__ __forceinline__ f32x16 zero16() {
    f32x16 z;
    #pragma unroll
    for (int i = 0; i < 16; i++) z[i] = 0.f;
    return z;
}

// ---------------- W fp32 -> bf16 (ws), vectorized ----------------
__global__ __launch_bounds__(256) void convert_w_kernel(
    const float* __restrict__ Wq, const float* __restrict__ Wk,
    const float* __restrict__ Wv, __bf16* __restrict__ wb)
{
    int i = blockIdx.x * 256 + threadIdx.x;      // 49152 threads, 4 elems each
    int m = i >> 14, off = (i & 16383) << 2;
    const float* s = (m == 0 ? Wq : (m == 1 ? Wk : Wv)) + off;
    float4 f = *(const float4*)s;
    bf16x4 h = { (__bf16)f.x, (__bf16)f.y, (__bf16)f.z, (__bf16)f.w };
    *(bf16x4*)(wb + (m << 16) + off) = h;
}

// ------ QKV projection (M=16384,N=192,K=1024) + fused RoPE + q-prescale ------
// 512 blocks x 32 rows, 8 waves (2M x 4N), reg-staged double-buffer.
__global__ __launch_bounds__(512, 2) void proj_kernel(
    const float* __restrict__ x, const __bf16* __restrict__ wb,
    __bf16* __restrict__ qb, __bf16* __restrict__ kb, __bf16* __restrict__ vt)
{
    __shared__ __bf16 xs[2][32][72];
    __shared__ __bf16 wl[2][192][72];
    const int tid  = threadIdx.x;
    const int wave = tid >> 6, lane = tid & 63;
    const int l15 = lane & 15, l4 = lane >> 4;
    const int wm = wave >> 2, wn = wave & 3;     // 2 M-halves x 4 N-groups
    const size_t m0 = (size_t)blockIdx.x * 32;
    const int xrow = tid >> 4, xc4 = (tid & 15) * 4;   // x stage: 16 thr/row
    const int wrow = tid >> 3, wcp = (tid & 7) * 8;    // W stage: +64 rows per j

    f32x4 acc[3];
    #pragma unroll
    for (int bn = 0; bn < 3; bn++) acc[bn] = (f32x4){0.f, 0.f, 0.f, 0.f};

    const float* xsrc = x + (m0 + xrow) * 1024 + xc4;

    float4 rx;
    bf16x8 rw[3];

    // prologue: tile 0 -> regs -> LDS buf 0
    rx = *(const float4*)(xsrc);
    #pragma unroll
    for (int j = 0; j < 3; j++)
        rw[j] = *(const bf16x8*)(wb + (size_t)(wrow + j * 64) * 1024 + wcp);
    {
        bf16x4 hx = {(__bf16)rx.x, (__bf16)rx.y, (__bf16)rx.z, (__bf16)rx.w};
        *(bf16x4*)&xs[0][xrow][xc4] = hx;
        #pragma unroll
        for (int j = 0; j < 3; j++)
            *(bf16x8*)&wl[0][wrow + j * 64][wcp] = rw[j];
    }
    __syncthreads();

    for (int t = 0; t < 16; t++) {
        const int cur = t & 1;
        if (t < 15) {   // issue next tile's loads early (overlap with compute)
            const int k0 = (t + 1) * 64;
            rx = *(const float4*)(xsrc + k0);
            #pragma unroll
            for (int j = 0; j < 3; j++)
                rw[j] = *(const bf16x8*)(wb + (size_t)(wrow + j * 64) * 1024 + k0 + wcp);
        }
        // compute tile t from LDS[cur]
        bf16x8 af[2], bfr[3][2];
        #pragma unroll
        for (int c = 0; c < 2; c++)
            af[c] = *(const bf16x8*)&xs[cur][wm * 16 + l15][c * 32 + l4 * 8];
        #pragma unroll
        for (int nf = 0; nf < 3; nf++)
            #pragma unroll
            for (int c = 0; c < 2; c++)
                bfr[nf][c] = *(const bf16x8*)&wl[cur][wn * 48 + nf * 16 + l15][c * 32 + l4 * 8];
        #pragma unroll
        for (int nf = 0; nf < 3; nf++)
            #pragma unroll
            for (int c = 0; c < 2; c++)
                acc[nf] = mfma16(af[c], bfr[nf][c], acc[nf]);
        if (t < 15) {   // stage tile t+1 into the other buffer
            bf16x4 hx = {(__bf16)rx.x, (__bf16)rx.y, (__bf16)rx.z, (__bf16)rx.w};
            *(bf16x4*)&xs[cur ^ 1][xrow][xc4] = hx;
            #pragma unroll
            for (int j = 0; j < 3; j++)
                *(bf16x8*)&wl[cur ^ 1][wrow + j * 64][wcp] = rw[j];
        }
        __syncthreads();
    }

    // epilogue: C layout col = l15 (n), row = l4*4 + r (m); rope fused for q,k;
    // q additionally pre-scaled by (1/8)*log2(e) so flash softmax is base-2 direct.
    #pragma unroll
    for (int nf = 0; nf < 3; nf++) {
        int n = wn * 48 + nf * 16 + l15;
        #pragma unroll
        for (int r = 0; r < 4; r++) {
            size_t mrow = m0 + wm * 16 + l4 * 4 + r;
            float val = acc[nf][r];
            float partner = __shfl_xor(val, 1);
            if (n < 128) {
                int i = (n & 63) >> 1;
                int t = (int)(mrow & 4095);
                float inv = __builtin_exp2f((float)i * (-13.287712379549449f / 32.f));
                float ang = (float)t * inv;
                float sn, cs;
                __sincosf(ang, &sn, &cs);
                float res = (n & 1) ? (partner * sn + val * cs)
                                    : (val * cs - partner * sn);
                if (n < 64) {
                    res *= 0.180336884f;    // (1/8)*log2(e) folded into q
                    qb[mrow * 64 + n] = (__bf16)res;
                } else {
                    kb[mrow * 64 + (n - 64)] = (__bf16)res;
                }
            } else {
                int bb = (int)(mrow >> 12), tt = (int)(mrow & 4095);
                vt[((size_t)bb * 64 + (n - 128)) * 4096 + tt] = (__bf16)val;
            }
        }
    }
}

// ---------------- causal flash attention, 1024-thread blocks ----------------
// 256 blocks = 1/CU. XCD-affine: b=(blk&7)>>1. Serial heavy (127-p) + light (p)
// halves -> balanced per CU. 16 waves = 16-way split-K over 64-row k-tiles.
// Swapped QK^T (lane -> one q col); K rows pi-permuted -> P repack is a register
// rename. Softmax is PURELY lane-local: each lane tracks (m,l) for its own
// h-half k-rows; no cross-lane ops in the loop. The two halves are merged as 32
// virtual splits in the epilogue (weight chosen by hd=(d>>2)&1, exact).
__global__ __launch_bounds__(1024) void flash_kernel(
    const __bf16* __restrict__ qb, const __bf16* __restrict__ kb,
    const __bf16* __restrict__ vt, float* __restrict__ out)
{
    __shared__ float ods[16][32][36];       // two-pass merge buffer (o0 then o1)
    __shared__ float mls[2][16][2][32];     // m,l per (wave, h, q)

    const int tid = threadIdx.x;
    const int wave = tid >> 6, lane = tid & 63;
    const int l31 = lane & 31, h = lane >> 5;
    const int xcd = blockIdx.x & 7;
    const int b = xcd >> 1;
    const int p = ((blockIdx.x >> 3) << 1) | (xcd & 1);   // 0..63 per batch
    // pi bit-shuffle: [b4 b3 b2 b1 b0] -> row with b3->16s, b2->8s, b4->4s
    const int prow = ((l31 >> 3) & 1) * 16 + ((l31 >> 2) & 1) * 8
                   + (l31 >> 4) * 4 + (l31 & 3);

    const __bf16* kbb = kb + (size_t)b * T_LEN * 64;
    const __bf16* vtb = vt + (size_t)b * 64 * T_LEN;

    #pragma unroll 1
    for (int half = 0; half < 2; half++) {
        const int jt = half ? p : 127 - p;
        const int q0 = jt * 32;
        const int qg = q0 + l31;

        // Q B-frags: col q = l31, k(d) = dc*16 + 8h + j  (q pre-scaled in proj)
        const __bf16* qp = qb + ((size_t)b * T_LEN + q0 + l31) * 64 + h * 8;
        bf16x8 qf[4];
        #pragma unroll
        for (int dc = 0; dc < 4; dc++) qf[dc] = *(const bf16x8*)(qp + dc * 16);

        float m = 16.f, l = 0.f;
        f32x16 o0 = zero16(), o1 = zero16();
        const int nt = (jt >> 1) + 1;   // 64-row k-tiles

        #pragma unroll 1
        for (int kt = wave; kt < nt; kt += 16) {
            const int kc0 = kt << 6;
            // K + V frags issued together at iter start
            const __bf16* kr = kbb + (size_t)(kc0 + prow) * 64 + h * 8;
            bf16x8 kf[8];
            #pragma unroll
            for (int dc = 0; dc < 4; dc++) {
                kf[dc]     = *(const bf16x8*)(kr + dc * 16);
                kf[4 + dc] = *(const bf16x8*)(kr + 2048 + dc * 16);   // +32 rows
            }
            const __bf16* vr0 = vtb + (size_t)l31 * T_LEN + kc0 + h * 8;
            const __bf16* vr1 = vr0 + (size_t)32 * T_LEN;
            bf16x8 vf0[4], vf1[4];
            #pragma unroll
            for (int cg = 0; cg < 4; cg++) {
                vf0[cg] = *(const bf16x8*)(vr0 + cg * 16);
                vf1[cg] = *(const bf16x8*)(vr1 + cg * 16);
            }
            // QK^T
            f32x16 s0 = zero16(), s1 = zero16();
            __builtin_amdgcn_s_setprio(1);
            #pragma unroll
            for (int dc = 0; dc < 4; dc++) {
                s0 = mfma32(kf[dc], qf[dc], s0);
                s1 = mfma32(kf[4 + dc], qf[dc], s1);
            }
            __builtin_amdgcn_s_setprio(0);
            // causal mask: only diagonal-straddling tiles (wave-uniform guard)
            if (kc0 + 63 > q0) {
                #pragma unroll
                for (int r = 0; r < 16; r++) {
                    int koff = kc0 + ((r >> 2) & 1) * 16 + 8 * h
                             + (r >> 3) * 4 + (r & 3);
                    if (koff > qg)      s0[r] = -1e30f;
                    if (koff + 32 > qg) s1[r] = -1e30f;
                }
            }
            // per-lane tile max (defer check only; no cross-lane traffic)
            float tm[8];
            #pragma unroll
            for (int i = 0; i < 8; i++)
                tm[i] = fmaxf(fmaxf(s0[2 * i], s0[2 * i + 1]),
                              fmaxf(s1[2 * i], s1[2 * i + 1]));
            #pragma unroll
            for (int i = 0; i < 4; i++) tm[i] = fmaxf(tm[i], tm[i + 4]);
            const float tmax = fmaxf(fmaxf(tm[0], tm[1]), fmaxf(tm[2], tm[3]));
            // exp2 against running per-lane base m
            float ts[4] = {0.f, 0.f, 0.f, 0.f};
            #pragma unroll
            for (int r = 0; r < 16; r++) {
                float e0 = __builtin_exp2f(s0[r] - m);
                float e1 = __builtin_exp2f(s1[r] - m);
                s0[r] = e0; s1[r] = e1;
                ts[r & 3] += e0 + e1;
            }
            l += (ts[0] + ts[1]) + (ts[2] + ts[3]);
            // P -> B-frags: pure register rename under pi (no shuffles)
            union { u32 w[4]; bf16x8 v; } pf[4];
            #pragma unroll
            for (int cg = 0; cg < 2; cg++) {
                pf[cg].w[0]     = packbf(s0[4 * cg + 0],  s0[4 * cg + 1]);
                pf[cg].w[1]     = packbf(s0[4 * cg + 2],  s0[4 * cg + 3]);
                pf[cg].w[2]     = packbf(s0[4 * cg + 8],  s0[4 * cg + 9]);
                pf[cg].w[3]     = packbf(s0[4 * cg + 10], s0[4 * cg + 11]);
                pf[cg + 2].w[0] = packbf(s1[4 * cg + 0],  s1[4 * cg + 1]);
                pf[cg + 2].w[1] = packbf(s1[4 * cg + 2],  s1[4 * cg + 3]);
                pf[cg + 2].w[2] = packbf(s1[4 * cg + 8],  s1[4 * cg + 9]);
                pf[cg + 2].w[3] = packbf(s1[4 * cg + 10], s1[4 * cg + 11]);
            }
            // PV: O^T += V^T P^T
            __builtin_amdgcn_s_setprio(1);
            #pragma unroll
            for (int cg = 0; cg < 4; cg++) {
                o0 = mfma32(vf0[cg], pf[cg].v, o0);
                o1 = mfma32(vf1[cg], pf[cg].v, o1);
            }
            __builtin_amdgcn_s_setprio(0);
            // defer-rescale (wave-uniform branch; per-lane base m)
            if (!__all(tmax <= m + 8.f)) {
                const float mnew = fmaxf(m, tmax);
                const float alpha = __builtin_exp2f(m - mnew);
                m = mnew;
                l *= alpha;
                #pragma unroll
                for (int r = 0; r < 16; r++) { o0[r] *= alpha; o1[r] *= alpha; }
            }
        }

        // ---- publish + two-pass merge over 32 virtual splits (wave, h) ----
        // O^T C-layout col q=l31, row d=(r&3)+8*(r>>2)+4h (+32 for o1)
        #pragma unroll
        for (int c2 = 0; c2 < 4; c2++) {
            f32x4 w0 = {o0[4 * c2], o0[4 * c2 + 1], o0[4 * c2 + 2], o0[4 * c2 + 3]};
            *(f32x4*)&ods[wave][l31][8 * c2 + 4 * h] = w0;
        }
        mls[0][wave][h][l31] = m;
        mls[1][wave][h][l31] = l;
        __syncthreads();

        const int q = tid >> 5, dcm = tid & 31;
        const int hd = (dcm >> 2) & 1;   // which h produced output row d
        float M = -1e30f;
        #pragma unroll
        for (int s2 = 0; s2 < 16; s2++)
            M = fmaxf(M, fmaxf(mls[0][s2][0][q], mls[0][s2][1][q]));
        float wsel[16], L = 0.f;
        #pragma unroll
        for (int s2 = 0; s2 < 16; s2++) {
            float w0 = __builtin_exp2f(mls[0][s2][0][q] - M);
            float w1 = __builtin_exp2f(mls[0][s2][1][q] - M);
            L += w0 * mls[1][s2][0][q] + w1 * mls[1][s2][1][q];
            wsel[s2] = hd ? w1 : w0;
        }
        const float invL = 1.f / L;
        float accA = 0.f;
        #pragma unroll
        for (int s2 = 0; s2 < 16; s2++) accA += wsel[s2] * ods[s2][q][dcm];
        out[((size_t)b * T_LEN + q0 + q) * 64 + dcm] = accA * invL;
        __syncthreads();
        // pass B: d = 32..63 (o1); same hd/wsel apply
        #pragma unroll
        for (int c2 = 0; c2 < 4; c2++) {
            f32x4 w1v = {o1[4 * c2], o1[4 * c2 + 1], o1[4 * c2 + 2], o1[4 * c2 + 3]};
            *(f32x4*)&ods[wave][l31][8 * c2 + 4 * h] = w1v;
        }
        __syncthreads();
        float accB = 0.f;
        #pragma unroll
        for (int s2 = 0; s2 < 16; s2++) accB += wsel[s2] * ods[s2][q][dcm];
        out[((size_t)b * T_LEN + q0 + q) * 64 + 32 + dcm] = accB * invL;
        __syncthreads();
    }
}

extern "C" void kernel_launch(void* const* d_in, const int* in_sizes, int n_in,
                              void* d_out, int out_size, void* d_ws, size_t ws_size,
                              hipStream_t stream)
{
    const float* x  = (const float*)d_in[0];
    const float* Wq = (const float*)d_in[1];
    const float* Wk = (const float*)d_in[2];
    const float* Wv = (const float*)d_in[3];
    float* out = (float*)d_out;

    __bf16* qb = (__bf16*)d_ws;          // 2 MB (rope applied, pre-scaled)
    __bf16* kb = qb + 1048576;           // 2 MB (rope applied)
    __bf16* vt = kb + 1048576;           // 2 MB (V transposed [b][d][t])
    __bf16* wb = vt + 1048576;           // 384 KB

    convert_w_kernel<<<192, 256, 0, stream>>>(Wq, Wk, Wv, wb);
    proj_kernel<<<512, 512, 0, stream>>>(x, wb, qb, kb, vt);
    flash_kernel<<<256, 1024, 0, stream>>>(qb, kb, vt, out);
}

// Round 12
// 62.485 us; speedup vs baseline: 1.5456x; 1.5456x over previous
//
#include <hip/hip_runtime.h>

typedef __bf16 bf16x8 __attribute__((ext_vector_type(8)));
typedef __bf16 bf16x4 __attribute__((ext_vector_type(4)));
typedef float f32x4 __attribute__((ext_vector_type(4)));
typedef float f32x16 __attribute__((ext_vector_type(16)));
typedef unsigned int u32;

#define T_LEN 4096

__device__ __forceinline__ f32x4 mfma16(bf16x8 a, bf16x8 b, f32x4 c) {
    return __builtin_amdgcn_mfma_f32_16x16x32_bf16(a, b, c, 0, 0, 0);
}
__device__ __forceinline__ f32x16 mfma32(bf16x8 a, bf16x8 b, f32x16 c) {
    return __builtin_amdgcn_mfma_f32_32x32x16_bf16(a, b, c, 0, 0, 0);
}
__device__ __forceinline__ u32 packbf(float lo, float hi) {
    union { __bf16 e[2]; u32 w; } u;
    u.e[0] = (__bf16)lo; u.e[1] = (__bf16)hi;
    return u.w;
}
__device__ __forceinline__ f32x16 zero16() {
    f32x16 z;
    #pragma unroll
    for (int i = 0; i < 16; i++) z[i] = 0.f;
    return z;
}

// ---------------- W fp32 -> bf16 (ws), vectorized ----------------
__global__ __launch_bounds__(256) void convert_w_kernel(
    const float* __restrict__ Wq, const float* __restrict__ Wk,
    const float* __restrict__ Wv, __bf16* __restrict__ wb)
{
    int i = blockIdx.x * 256 + threadIdx.x;      // 49152 threads, 4 elems each
    int m = i >> 14, off = (i & 16383) << 2;
    const float* s = (m == 0 ? Wq : (m == 1 ? Wk : Wv)) + off;
    float4 f = *(const float4*)s;
    bf16x4 h = { (__bf16)f.x, (__bf16)f.y, (__bf16)f.z, (__bf16)f.w };
    *(bf16x4*)(wb + (m << 16) + off) = h;
}

// ------ QKV projection (M=16384,N=192,K=1024) + fused RoPE + q-prescale ------
// 512 blocks x 32 rows, 8 waves (2M x 4N), reg-staged double-buffer.
// Epilogue stores Q/K/V in FRAGMENT-NATIVE tiled layouts (per batch, bf16 elems):
//   Q: qfb[tile(q>>5)*2048 + (d>>4)*512 + ((q&31)+32*((d>>3)&1))*8 + (d&7)]
//   K: kfb[tile(t>>5)*2048 + (d>>4)*512 + (pi_inv(t&31)+32*((d>>3)&1))*8 + (d&7)]
//   V: vfb[tile(t>>5)*2048 + (((d>>5)<<1)|((t&31)>>4))*512 + ((d&31)+32*((t>>3)&1))*8 + (t&7)]
// so flash fragment loads are lane-consecutive (coalesced, 16 lines/inst).
__global__ __launch_bounds__(512, 2) void proj_kernel(
    const float* __restrict__ x, const __bf16* __restrict__ wb,
    __bf16* __restrict__ qfb, __bf16* __restrict__ kfb, __bf16* __restrict__ vfb)
{
    __shared__ __bf16 xs[2][32][72];
    __shared__ __bf16 wl[2][192][72];
    const int tid  = threadIdx.x;
    const int wave = tid >> 6, lane = tid & 63;
    const int l15 = lane & 15, l4 = lane >> 4;
    const int wm = wave >> 2, wn = wave & 3;     // 2 M-halves x 4 N-groups
    const size_t m0 = (size_t)blockIdx.x * 32;
    const int xrow = tid >> 4, xc4 = (tid & 15) * 4;   // x stage: 16 thr/row
    const int wrow = tid >> 3, wcp = (tid & 7) * 8;    // W stage: +64 rows per j

    f32x4 acc[3];
    #pragma unroll
    for (int bn = 0; bn < 3; bn++) acc[bn] = (f32x4){0.f, 0.f, 0.f, 0.f};

    const float* xsrc = x + (m0 + xrow) * 1024 + xc4;

    float4 rx;
    bf16x8 rw[3];

    // prologue: tile 0 -> regs -> LDS buf 0
    rx = *(const float4*)(xsrc);
    #pragma unroll
    for (int j = 0; j < 3; j++)
        rw[j] = *(const bf16x8*)(wb + (size_t)(wrow + j * 64) * 1024 + wcp);
    {
        bf16x4 hx = {(__bf16)rx.x, (__bf16)rx.y, (__bf16)rx.z, (__bf16)rx.w};
        *(bf16x4*)&xs[0][xrow][xc4] = hx;
        #pragma unroll
        for (int j = 0; j < 3; j++)
            *(bf16x8*)&wl[0][wrow + j * 64][wcp] = rw[j];
    }
    __syncthreads();

    for (int t = 0; t < 16; t++) {
        const int cur = t & 1;
        if (t < 15) {   // issue next tile's loads early (overlap with compute)
            const int k0 = (t + 1) * 64;
            rx = *(const float4*)(xsrc + k0);
            #pragma unroll
            for (int j = 0; j < 3; j++)
                rw[j] = *(const bf16x8*)(wb + (size_t)(wrow + j * 64) * 1024 + k0 + wcp);
        }
        // compute tile t from LDS[cur]
        bf16x8 af[2], bfr[3][2];
        #pragma unroll
        for (int c = 0; c < 2; c++)
            af[c] = *(const bf16x8*)&xs[cur][wm * 16 + l15][c * 32 + l4 * 8];
        #pragma unroll
        for (int nf = 0; nf < 3; nf++)
            #pragma unroll
            for (int c = 0; c < 2; c++)
                bfr[nf][c] = *(const bf16x8*)&wl[cur][wn * 48 + nf * 16 + l15][c * 32 + l4 * 8];
        #pragma unroll
        for (int nf = 0; nf < 3; nf++)
            #pragma unroll
            for (int c = 0; c < 2; c++)
                acc[nf] = mfma16(af[c], bfr[nf][c], acc[nf]);
        if (t < 15) {   // stage tile t+1 into the other buffer
            bf16x4 hx = {(__bf16)rx.x, (__bf16)rx.y, (__bf16)rx.z, (__bf16)rx.w};
            *(bf16x4*)&xs[cur ^ 1][xrow][xc4] = hx;
            #pragma unroll
            for (int j = 0; j < 3; j++)
                *(bf16x8*)&wl[cur ^ 1][wrow + j * 64][wcp] = rw[j];
        }
        __syncthreads();
    }

    // epilogue: C layout col = l15 (n), row = l4*4 + r (m); rope fused for q,k;
    // q pre-scaled by (1/8)*log2(e); stores go to fragment-native layouts.
    #pragma unroll
    for (int nf = 0; nf < 3; nf++) {
        int n = wn * 48 + nf * 16 + l15;
        #pragma unroll
        for (int r = 0; r < 4; r++) {
            size_t mrow = m0 + wm * 16 + l4 * 4 + r;
            float val = acc[nf][r];
            float partner = __shfl_xor(val, 1);
            const int bb = (int)(mrow >> 12);
            const int tq = (int)(mrow & 4095);
            const size_t bbase = (size_t)bb * 262144;
            if (n < 128) {
                int i = (n & 63) >> 1;
                float inv = __builtin_exp2f((float)i * (-13.287712379549449f / 32.f));
                float ang = (float)tq * inv;
                float sn, cs;
                __sincosf(ang, &sn, &cs);
                float res = (n & 1) ? (partner * sn + val * cs)
                                    : (val * cs - partner * sn);
                if (n < 64) {
                    res *= 0.180336884f;    // (1/8)*log2(e) folded into q
                    int d = n;
                    size_t idx = bbase + (size_t)(tq >> 5) * 2048 + (d >> 4) * 512
                               + ((tq & 31) + ((d >> 3) & 1) * 32) * 8 + (d & 7);
                    qfb[idx] = (__bf16)res;
                } else {
                    int d = n - 64, rr = tq & 31;
                    int l31i = ((rr >> 2) & 1) * 16 + ((rr >> 4) & 1) * 8
                             + ((rr >> 3) & 1) * 4 + (rr & 3);   // pi^-1
                    size_t idx = bbase + (size_t)(tq >> 5) * 2048 + (d >> 4) * 512
                               + (l31i + ((d >> 3) & 1) * 32) * 8 + (d & 7);
                    kfb[idx] = (__bf16)res;
                }
            } else {
                int d = n - 128;
                int cc = ((d >> 5) << 1) | ((tq & 31) >> 4);
                size_t idx = bbase + (size_t)(tq >> 5) * 2048 + cc * 512
                           + ((d & 31) + ((tq >> 3) & 1) * 32) * 8 + (tq & 7);
                vfb[idx] = (__bf16)val;
            }
        }
    }
}

// ---------------- causal flash attention, 1024-thread blocks ----------------
// 256 blocks = 1/CU. XCD-affine: b=(blk&7)>>1. Serial heavy (127-p) + light (p)
// halves -> balanced per CU. 16 waves = 16-way split-K over 32-row k-tiles.
// Swapped QK^T (lane -> one q col); fragment-native layouts make every load
// lane-consecutive (coalesced). pi permutation baked into kfb at store time;
// P->B-frag repack is a pure register rename. exp2 uses running base m.
__global__ __launch_bounds__(1024) void flash_kernel(
    const __bf16* __restrict__ qfb, const __bf16* __restrict__ kfb,
    const __bf16* __restrict__ vfb, float* __restrict__ out)
{
    __shared__ float ods[16][32][36];   // two-pass merge buffer (o0 then o1)
    __shared__ float mls[2][16][32];

    const int tid = threadIdx.x;
    const int wave = tid >> 6, lane = tid & 63;
    const int l31 = lane & 31, h = lane >> 5;
    const int xcd = blockIdx.x & 7;
    const int b = xcd >> 1;
    const int p = ((blockIdx.x >> 3) << 1) | (xcd & 1);   // 0..63 per batch

    const __bf16* qb_b = qfb + (size_t)b * 262144;
    const __bf16* kb_b = kfb + (size_t)b * 262144;
    const __bf16* vb_b = vfb + (size_t)b * 262144;

    #pragma unroll 1
    for (int half = 0; half < 2; half++) {
        const int jt = half ? p : 127 - p;
        const int q0 = jt * 32;
        const int qg = q0 + l31;

        // Q B-frags: coalesced tile load
        const __bf16* qp = qb_b + (size_t)jt * 2048 + lane * 8;
        bf16x8 qf[4];
        #pragma unroll
        for (int dc = 0; dc < 4; dc++) qf[dc] = *(const bf16x8*)(qp + dc * 512);

        float m = 16.f, l = 0.f;
        f32x16 o0 = zero16(), o1 = zero16();
        const int nt = jt + 1;   // 32-row k-tiles

        #pragma unroll 1
        for (int kt = wave; kt < nt; kt += 16) {
            const int kc0 = kt << 5;
            // K + V frags: coalesced tile loads
            const __bf16* kr = kb_b + (size_t)kt * 2048 + lane * 8;
            bf16x8 kf0 = *(const bf16x8*)(kr);
            bf16x8 kf1 = *(const bf16x8*)(kr + 512);
            bf16x8 kf2 = *(const bf16x8*)(kr + 1024);
            bf16x8 kf3 = *(const bf16x8*)(kr + 1536);
            const __bf16* vr = vb_b + (size_t)kt * 2048 + lane * 8;
            bf16x8 vf00 = *(const bf16x8*)(vr);          // d 0..31,  cg 0
            bf16x8 vf01 = *(const bf16x8*)(vr + 512);    // d 0..31,  cg 1
            bf16x8 vf10 = *(const bf16x8*)(vr + 1024);   // d 32..63, cg 0
            bf16x8 vf11 = *(const bf16x8*)(vr + 1536);   // d 32..63, cg 1
            f32x16 s = zero16();
            __builtin_amdgcn_s_setprio(1);
            s = mfma32(kf0, qf[0], s);
            s = mfma32(kf1, qf[1], s);
            s = mfma32(kf2, qf[2], s);
            s = mfma32(kf3, qf[3], s);
            __builtin_amdgcn_s_setprio(0);
            // causal mask: only the diagonal tile straddles
            if (kt == jt) {
                #pragma unroll
                for (int r = 0; r < 16; r++) {
                    int pioff = ((r >> 2) & 1) * 16 + 8 * h + (r >> 3) * 4 + (r & 3);
                    if (kc0 + pioff > qg) s[r] = -1e30f;
                }
            }
            // local max tree (defer check only; does NOT gate the exp)
            float tm[8];
            #pragma unroll
            for (int i = 0; i < 8; i++) tm[i] = fmaxf(s[2 * i], s[2 * i + 1]);
            #pragma unroll
            for (int i = 0; i < 4; i++) tm[i] = fmaxf(tm[i], tm[i + 4]);
            float tmax = fmaxf(fmaxf(tm[0], tm[1]), fmaxf(tm[2], tm[3]));
            // exp2 against running base m — no reduction wait on critical path
            float ts[4] = {0.f, 0.f, 0.f, 0.f};
            #pragma unroll
            for (int r = 0; r < 16; r++) {
                float e = __builtin_exp2f(s[r] - m);
                s[r] = e;
                ts[r & 3] += e;
            }
            float lsum = (ts[0] + ts[1]) + (ts[2] + ts[3]);
            // cross-half exchanges issued now, consumed after PV
            float lsum_p = __shfl_xor(lsum, 32);
            float tmax_p = __shfl_xor(tmax, 32);
            // P -> B-frags: pure register rename under pi (no shuffles)
            union { u32 w[4]; bf16x8 v; } pf[2];
            #pragma unroll
            for (int cg = 0; cg < 2; cg++) {
                pf[cg].w[0] = packbf(s[4 * cg + 0],  s[4 * cg + 1]);
                pf[cg].w[1] = packbf(s[4 * cg + 2],  s[4 * cg + 3]);
                pf[cg].w[2] = packbf(s[4 * cg + 8],  s[4 * cg + 9]);
                pf[cg].w[3] = packbf(s[4 * cg + 10], s[4 * cg + 11]);
            }
            // PV: O^T += V^T P^T
            __builtin_amdgcn_s_setprio(1);
            o0 = mfma32(vf00, pf[0].v, o0);
            o0 = mfma32(vf01, pf[1].v, o0);
            o1 = mfma32(vf10, pf[0].v, o1);
            o1 = mfma32(vf11, pf[1].v, o1);
            __builtin_amdgcn_s_setprio(0);
            // fold reductions; rescale AFTER accumulation (tile used base m)
            l += lsum + lsum_p;
            float tmx = fmaxf(tmax, tmax_p);
            if (!__all(tmx <= m + 8.f)) {
                const float mnew = fmaxf(m, tmx);
                const float alpha = __builtin_exp2f(m - mnew);
                m = mnew;
                l *= alpha;
                #pragma unroll
                for (int r = 0; r < 16; r++) { o0[r] *= alpha; o1[r] *= alpha; }
            }
        }

        // ---- two-pass 16-way merge; O^T C-layout col q=l31, row d=(r&3)+8*(r>>2)+4h
        const int q = tid >> 5, dcm = tid & 31;
        // pass A: d = 0..31 (o0)
        #pragma unroll
        for (int c2 = 0; c2 < 4; c2++) {
            f32x4 w0 = {o0[4 * c2], o0[4 * c2 + 1], o0[4 * c2 + 2], o0[4 * c2 + 3]};
            *(f32x4*)&ods[wave][l31][8 * c2 + 4 * h] = w0;
        }
        if (h == 0) {
            mls[0][wave][l31] = (wave < nt) ? m : -1e30f;   // empty splits: weight 0
            mls[1][wave][l31] = l;
        }
        __syncthreads();
        float M = -1e30f;
        #pragma unroll
        for (int s2 = 0; s2 < 16; s2++) M = fmaxf(M, mls[0][s2][q]);
        float w16[16], L = 0.f;
        #pragma unroll
        for (int s2 = 0; s2 < 16; s2++) {
            float ws = __builtin_exp2f(mls[0][s2][q] - M);
            w16[s2] = ws;
            L += ws * mls[1][s2][q];
        }
        const float invL = 1.f / L;
        float accA = 0.f;
        #pragma unroll
        for (int s2 = 0; s2 < 16; s2++) accA += w16[s2] * ods[s2][q][dcm];
        out[((size_t)b * T_LEN + q0 + q) * 64 + dcm] = accA * invL;
        __syncthreads();
        // pass B: d = 32..63 (o1)
        #pragma unroll
        for (int c2 = 0; c2 < 4; c2++) {
            f32x4 w1 = {o1[4 * c2], o1[4 * c2 + 1], o1[4 * c2 + 2], o1[4 * c2 + 3]};
            *(f32x4*)&ods[wave][l31][8 * c2 + 4 * h] = w1;
        }
        __syncthreads();
        float accB = 0.f;
        #pragma unroll
        for (int s2 = 0; s2 < 16; s2++) accB += w16[s2] * ods[s2][q][dcm];
        out[((size_t)b * T_LEN + q0 + q) * 64 + 32 + dcm] = accB * invL;
        __syncthreads();
    }
}

extern "C" void kernel_launch(void* const* d_in, const int* in_sizes, int n_in,
                              void* d_out, int out_size, void* d_ws, size_t ws_size,
                              hipStream_t stream)
{
    const float* x  = (const float*)d_in[0];
    const float* Wq = (const float*)d_in[1];
    const float* Wk = (const float*)d_in[2];
    const float* Wv = (const float*)d_in[3];
    float* out = (float*)d_out;

    __bf16* qfb = (__bf16*)d_ws;         // 2 MB, fragment-native (rope+prescale)
    __bf16* kfb = qfb + 1048576;         // 2 MB, fragment-native (rope, pi-permuted)
    __bf16* vfb = kfb + 1048576;         // 2 MB, fragment-native (PV operand order)
    __bf16* wb  = vfb + 1048576;         // 384 KB

    convert_w_kernel<<<192, 256, 0, stream>>>(Wq, Wk, Wv, wb);
    proj_kernel<<<512, 512, 0, stream>>>(x, wb, qfb, kfb, vfb);
    flash_kernel<<<256, 1024, 0, stream>>>(qfb, kfb, vfb, out);
}

// Round 13
// 54.134 us; speedup vs baseline: 1.7841x; 1.1543x over previous
//
#include <hip/hip_runtime.h>

typedef __bf16 bf16x8 __attribute__((ext_vector_type(8)));
typedef __bf16 bf16x4 __attribute__((ext_vector_type(4)));
typedef float f32x4 __attribute__((ext_vector_type(4)));
typedef float f32x16 __attribute__((ext_vector_type(16)));
typedef unsigned int u32;

#define T_LEN 4096

__device__ __forceinline__ f32x4 mfma16(bf16x8 a, bf16x8 b, f32x4 c) {
    return __builtin_amdgcn_mfma_f32_16x16x32_bf16(a, b, c, 0, 0, 0);
}
__device__ __forceinline__ f32x16 mfma32(bf16x8 a, bf16x8 b, f32x16 c) {
    return __builtin_amdgcn_mfma_f32_32x32x16_bf16(a, b, c, 0, 0, 0);
}
__device__ __forceinline__ u32 packbf(float lo, float hi) {
    union { __bf16 e[2]; u32 w; } u;
    u.e[0] = (__bf16)lo; u.e[1] = (__bf16)hi;
    return u.w;
}
__device__ __forceinline__ f32x16 zero16() {
    f32x16 z;
    #pragma unroll
    for (int i = 0; i < 16; i++) z[i] = 0.f;
    return z;
}

// ---------------- W fp32 -> bf16 (ws), vectorized ----------------
__global__ __launch_bounds__(256) void convert_w_kernel(
    const float* __restrict__ Wq, const float* __restrict__ Wk,
    const float* __restrict__ Wv, __bf16* __restrict__ wb)
{
    int i = blockIdx.x * 256 + threadIdx.x;      // 49152 threads, 4 elems each
    int m = i >> 14, off = (i & 16383) << 2;
    const float* s = (m == 0 ? Wq : (m == 1 ? Wk : Wv)) + off;
    float4 f = *(const float4*)s;
    bf16x4 h = { (__bf16)f.x, (__bf16)f.y, (__bf16)f.z, (__bf16)f.w };
    *(bf16x4*)(wb + (m << 16) + off) = h;
}

// ------ QKV projection (M=16384,N=192,K=1024) + fused RoPE + q-prescale ------
// 512 blocks x 32 rows, 8 waves (2M x 4N), reg-staged double-buffer; x 2-deep.
// Epilogue: rope'd results bounced through LDS (scalar writes into fragment-
// native intra-tile offsets), then stored with ONE coalesced bf16x4 per thread
// per output. Layouts (per batch, bf16 elems):
//   Q: qfb[tile(q>>5)*2048 + (d>>4)*512 + ((q&31)+32*((d>>3)&1))*8 + (d&7)]
//   K: kfb[tile(t>>5)*2048 + (d>>4)*512 + (pi_inv(t&31)+32*((d>>3)&1))*8 + (d&7)]
//   V: vfb[tile(t>>5)*2048 + (((d>>5)<<1)|((t&31)>>4))*512 + ((d&31)+32*((t>>3)&1))*8 + (t&7)]
__global__ __launch_bounds__(512, 2) void proj_kernel(
    const float* __restrict__ x, const __bf16* __restrict__ wb,
    __bf16* __restrict__ qfb, __bf16* __restrict__ kfb, __bf16* __restrict__ vfb)
{
    __shared__ __bf16 smem[4608 + 27648];   // xs[2][32][72] | wl[2][192][72]
    __bf16 (*xs)[32][72]  = (__bf16(*)[32][72])smem;
    __bf16 (*wl)[192][72] = (__bf16(*)[192][72])(smem + 4608);
    __bf16* stage = smem;                   // [3][2048] reused after the loop

    const int tid  = threadIdx.x;
    const int wave = tid >> 6, lane = tid & 63;
    const int l15 = lane & 15, l4 = lane >> 4;
    const int wm = wave >> 2, wn = wave & 3;     // 2 M-halves x 4 N-groups
    const size_t m0 = (size_t)blockIdx.x * 32;
    const int xrow = tid >> 4, xc4 = (tid & 15) * 4;   // x stage: 16 thr/row
    const int wrow = tid >> 3, wcp = (tid & 7) * 8;    // W stage: +64 rows per j

    f32x4 acc[3];
    #pragma unroll
    for (int bn = 0; bn < 3; bn++) acc[bn] = (f32x4){0.f, 0.f, 0.f, 0.f};

    const float* xsrc = x + (m0 + xrow) * 1024 + xc4;

    float4 rxA, rxB;
    bf16x8 rw[3];

    // prologue: x(0),W(0) -> LDS buf0; x(1) -> rxA
    {
        float4 r0 = *(const float4*)(xsrc);
        bf16x4 hx = {(__bf16)r0.x, (__bf16)r0.y, (__bf16)r0.z, (__bf16)r0.w};
        *(bf16x4*)&xs[0][xrow][xc4] = hx;
        #pragma unroll
        for (int j = 0; j < 3; j++) {
            rw[j] = *(const bf16x8*)(wb + (size_t)(wrow + j * 64) * 1024 + wcp);
            *(bf16x8*)&wl[0][wrow + j * 64][wcp] = rw[j];
        }
        rxA = *(const float4*)(xsrc + 64);
    }
    __syncthreads();

    for (int t = 0; t < 16; t++) {
        const int cur = t & 1;
        if (t < 14)   // x 2-deep: issue x(t+2) now (in flight ~2 iterations)
            rxB = *(const float4*)(xsrc + (t + 2) * 64);
        if (t < 15) { // W 1-deep (L2-resident)
            const int k0 = (t + 1) * 64;
            #pragma unroll
            for (int j = 0; j < 3; j++)
                rw[j] = *(const bf16x8*)(wb + (size_t)(wrow + j * 64) * 1024 + k0 + wcp);
        }
        // compute tile t from LDS[cur]
        bf16x8 af[2], bfr[3][2];
        #pragma unroll
        for (int c = 0; c < 2; c++)
            af[c] = *(const bf16x8*)&xs[cur][wm * 16 + l15][c * 32 + l4 * 8];
        #pragma unroll
        for (int nf = 0; nf < 3; nf++)
            #pragma unroll
            for (int c = 0; c < 2; c++)
                bfr[nf][c] = *(const bf16x8*)&wl[cur][wn * 48 + nf * 16 + l15][c * 32 + l4 * 8];
        #pragma unroll
        for (int nf = 0; nf < 3; nf++)
            #pragma unroll
            for (int c = 0; c < 2; c++)
                acc[nf] = mfma16(af[c], bfr[nf][c], acc[nf]);
        if (t < 15) {   // stage tile t+1 into the other buffer
            bf16x4 hx = {(__bf16)rxA.x, (__bf16)rxA.y, (__bf16)rxA.z, (__bf16)rxA.w};
            *(bf16x4*)&xs[cur ^ 1][xrow][xc4] = hx;
            #pragma unroll
            for (int j = 0; j < 3; j++)
                *(bf16x8*)&wl[cur ^ 1][wrow + j * 64][wcp] = rw[j];
        }
        rxA = rxB;
        __syncthreads();
    }
    // loop-final barrier passed: all LDS reads done; smem reusable as stage.

    // epilogue: C layout col = l15 (n), row = l4*4 + r (m); rope fused for q,k;
    // q pre-scaled by (1/8)*log2(e); scatter into LDS stage (cheap), then
    // coalesced tile copy-out.
    const int tq0 = (int)(m0 & 4095);   // 32-aligned
    #pragma unroll
    for (int nf = 0; nf < 3; nf++) {
        int n = wn * 48 + nf * 16 + l15;
        #pragma unroll
        for (int r = 0; r < 4; r++) {
            int row = wm * 16 + l4 * 4 + r;      // row within the 32-row tile
            float val = acc[nf][r];
            float partner = __shfl_xor(val, 1);
            if (n < 128) {
                int i = (n & 63) >> 1;
                float ang = (float)(tq0 + row)
                          * __builtin_exp2f((float)i * (-13.287712379549449f / 32.f));
                float sn, cs;
                __sincosf(ang, &sn, &cs);
                float res = (n & 1) ? (partner * sn + val * cs)
                                    : (val * cs - partner * sn);
                if (n < 64) {
                    res *= 0.180336884f;    // (1/8)*log2(e) folded into q
                    int d = n;
                    stage[(d >> 4) * 512 + (row + ((d >> 3) & 1) * 32) * 8 + (d & 7)]
                        = (__bf16)res;
                } else {
                    int d = n - 64;
                    int l31i = ((row >> 2) & 1) * 16 + ((row >> 4) & 1) * 8
                             + ((row >> 3) & 1) * 4 + (row & 3);   // pi^-1
                    stage[2048 + (d >> 4) * 512
                          + (l31i + ((d >> 3) & 1) * 32) * 8 + (d & 7)] = (__bf16)res;
                }
            } else {
                int d = n - 128;
                int cc = ((d >> 5) << 1) | ((row & 31) >> 4);
                stage[4096 + cc * 512
                      + ((d & 31) + ((row >> 3) & 1) * 32) * 8 + (row & 7)]
                    = (__bf16)val;
            }
        }
    }
    __syncthreads();
    {
        const size_t bbase = (size_t)(m0 >> 12) * 262144;
        const size_t tbase = (size_t)((m0 & 4095) >> 5) * 2048;
        bf16x4 q4 = *(const bf16x4*)&stage[tid * 4];
        bf16x4 k4 = *(const bf16x4*)&stage[2048 + tid * 4];
        bf16x4 v4 = *(const bf16x4*)&stage[4096 + tid * 4];
        *(bf16x4*)(qfb + bbase + tbase + tid * 4) = q4;
        *(bf16x4*)(kfb + bbase + tbase + tid * 4) = k4;
        *(bf16x4*)(vfb + bbase + tbase + tid * 4) = v4;
    }
}

// ---------------- causal flash attention, 1024-thread blocks ----------------
// 256 blocks = 1/CU. XCD-affine: b=(blk&7)>>1. Serial heavy (127-p) + light (p)
// halves -> balanced per CU. 16 waves = 16-way split-K over 32-row k-tiles.
// Swapped QK^T (lane -> one q col); fragment-native layouts make every load
// lane-consecutive (coalesced). pi permutation baked into kfb at store time;
// P->B-frag repack is a pure register rename. exp2 uses running base m.
__global__ __launch_bounds__(1024) void flash_kernel(
    const __bf16* __restrict__ qfb, const __bf16* __restrict__ kfb,
    const __bf16* __restrict__ vfb, float* __restrict__ out)
{
    __shared__ float ods[16][32][36];   // two-pass merge buffer (o0 then o1)
    __shared__ float mls[2][16][32];

    const int tid = threadIdx.x;
    const int wave = tid >> 6, lane = tid & 63;
    const int l31 = lane & 31, h = lane >> 5;
    const int xcd = blockIdx.x & 7;
    const int b = xcd >> 1;
    const int p = ((blockIdx.x >> 3) << 1) | (xcd & 1);   // 0..63 per batch

    const __bf16* qb_b = qfb + (size_t)b * 262144;
    const __bf16* kb_b = kfb + (size_t)b * 262144;
    const __bf16* vb_b = vfb + (size_t)b * 262144;

    #pragma unroll 1
    for (int half = 0; half < 2; half++) {
        const int jt = half ? p : 127 - p;
        const int q0 = jt * 32;
        const int qg = q0 + l31;

        // Q B-frags: coalesced tile load
        const __bf16* qp = qb_b + (size_t)jt * 2048 + lane * 8;
        bf16x8 qf[4];
        #pragma unroll
        for (int dc = 0; dc < 4; dc++) qf[dc] = *(const bf16x8*)(qp + dc * 512);

        float m = 16.f, l = 0.f;
        f32x16 o0 = zero16(), o1 = zero16();
        const int nt = jt + 1;   // 32-row k-tiles

        #pragma unroll 1
        for (int kt = wave; kt < nt; kt += 16) {
            const int kc0 = kt << 5;
            // K + V frags: coalesced tile loads
            const __bf16* kr = kb_b + (size_t)kt * 2048 + lane * 8;
            bf16x8 kf0 = *(const bf16x8*)(kr);
            bf16x8 kf1 = *(const bf16x8*)(kr + 512);
            bf16x8 kf2 = *(const bf16x8*)(kr + 1024);
            bf16x8 kf3 = *(const bf16x8*)(kr + 1536);
            const __bf16* vr = vb_b + (size_t)kt * 2048 + lane * 8;
            bf16x8 vf00 = *(const bf16x8*)(vr);          // d 0..31,  cg 0
            bf16x8 vf01 = *(const bf16x8*)(vr + 512);    // d 0..31,  cg 1
            bf16x8 vf10 = *(const bf16x8*)(vr + 1024);   // d 32..63, cg 0
            bf16x8 vf11 = *(const bf16x8*)(vr + 1536);   // d 32..63, cg 1
            f32x16 s = zero16();
            __builtin_amdgcn_s_setprio(1);
            s = mfma32(kf0, qf[0], s);
            s = mfma32(kf1, qf[1], s);
            s = mfma32(kf2, qf[2], s);
            s = mfma32(kf3, qf[3], s);
            __builtin_amdgcn_s_setprio(0);
            // causal mask: only the diagonal tile straddles
            if (kt == jt) {
                #pragma unroll
                for (int r = 0; r < 16; r++) {
                    int pioff = ((r >> 2) & 1) * 16 + 8 * h + (r >> 3) * 4 + (r & 3);
                    if (kc0 + pioff > qg) s[r] = -1e30f;
                }
            }
            // local max tree (defer check only; does NOT gate the exp)
            float tm[8];
            #pragma unroll
            for (int i = 0; i < 8; i++) tm[i] = fmaxf(s[2 * i], s[2 * i + 1]);
            #pragma unroll
            for (int i = 0; i < 4; i++) tm[i] = fmaxf(tm[i], tm[i + 4]);
            float tmax = fmaxf(fmaxf(tm[0], tm[1]), fmaxf(tm[2], tm[3]));
            // exp2 against running base m — no reduction wait on critical path
            float ts[4] = {0.f, 0.f, 0.f, 0.f};
            #pragma unroll
            for (int r = 0; r < 16; r++) {
                float e = __builtin_exp2f(s[r] - m);
                s[r] = e;
                ts[r & 3] += e;
            }
            float lsum = (ts[0] + ts[1]) + (ts[2] + ts[3]);
            // cross-half exchanges issued now, consumed after PV
            float lsum_p = __shfl_xor(lsum, 32);
            float tmax_p = __shfl_xor(tmax, 32);
            // P -> B-frags: pure register rename under pi (no shuffles)
            union { u32 w[4]; bf16x8 v; } pf[2];
            #pragma unroll
            for (int cg = 0; cg < 2; cg++) {
                pf[cg].w[0] = packbf(s[4 * cg + 0],  s[4 * cg + 1]);
                pf[cg].w[1] = packbf(s[4 * cg + 2],  s[4 * cg + 3]);
                pf[cg].w[2] = packbf(s[4 * cg + 8],  s[4 * cg + 9]);
                pf[cg].w[3] = packbf(s[4 * cg + 10], s[4 * cg + 11]);
            }
            // PV: O^T += V^T P^T
            __builtin_amdgcn_s_setprio(1);
            o0 = mfma32(vf00, pf[0].v, o0);
            o0 = mfma32(vf01, pf[1].v, o0);
            o1 = mfma32(vf10, pf[0].v, o1);
            o1 = mfma32(vf11, pf[1].v, o1);
            __builtin_amdgcn_s_setprio(0);
            // fold reductions; rescale AFTER accumulation (tile used base m)
            l += lsum + lsum_p;
            float tmx = fmaxf(tmax, tmax_p);
            if (!__all(tmx <= m + 8.f)) {
                const float mnew = fmaxf(m, tmx);
                const float alpha = __builtin_exp2f(m - mnew);
                m = mnew;
                l *= alpha;
                #pragma unroll
                for (int r = 0; r < 16; r++) { o0[r] *= alpha; o1[r] *= alpha; }
            }
        }

        // ---- two-pass 16-way merge; O^T C-layout col q=l31, row d=(r&3)+8*(r>>2)+4h
        const int q = tid >> 5, dcm = tid & 31;
        // pass A: d = 0..31 (o0)
        #pragma unroll
        for (int c2 = 0; c2 < 4; c2++) {
            f32x4 w0 = {o0[4 * c2], o0[4 * c2 + 1], o0[4 * c2 + 2], o0[4 * c2 + 3]};
            *(f32x4*)&ods[wave][l31][8 * c2 + 4 * h] = w0;
        }
        if (h == 0) {
            mls[0][wave][l31] = (wave < nt) ? m : -1e30f;   // empty splits: weight 0
            mls[1][wave][l31] = l;
        }
        __syncthreads();
        float M = -1e30f;
        #pragma unroll
        for (int s2 = 0; s2 < 16; s2++) M = fmaxf(M, mls[0][s2][q]);
        float w16[16], L = 0.f;
        #pragma unroll
        for (int s2 = 0; s2 < 16; s2++) {
            float ws = __builtin_exp2f(mls[0][s2][q] - M);
            w16[s2] = ws;
            L += ws * mls[1][s2][q];
        }
        const float invL = 1.f / L;
        float accA = 0.f;
        #pragma unroll
        for (int s2 = 0; s2 < 16; s2++) accA += w16[s2] * ods[s2][q][dcm];
        out[((size_t)b * T_LEN + q0 + q) * 64 + dcm] = accA * invL;
        __syncthreads();
        // pass B: d = 32..63 (o1)
        #pragma unroll
        for (int c2 = 0; c2 < 4; c2++) {
            f32x4 w1 = {o1[4 * c2], o1[4 * c2 + 1], o1[4 * c2 + 2], o1[4 * c2 + 3]};
            *(f32x4*)&ods[wave][l31][8 * c2 + 4 * h] = w1;
        }
        __syncthreads();
        float accB = 0.f;
        #pragma unroll
        for (int s2 = 0; s2 < 16; s2++) accB += w16[s2] * ods[s2][q][dcm];
        out[((size_t)b * T_LEN + q0 + q) * 64 + 32 + dcm] = accB * invL;
        __syncthreads();
    }
}

extern "C" void kernel_launch(void* const* d_in, const int* in_sizes, int n_in,
                              void* d_out, int out_size, void* d_ws, size_t ws_size,
                              hipStream_t stream)
{
    const float* x  = (const float*)d_in[0];
    const float* Wq = (const float*)d_in[1];
    const float* Wk = (const float*)d_in[2];
    const float* Wv = (const float*)d_in[3];
    float* out = (float*)d_out;

    __bf16* qfb = (__bf16*)d_ws;         // 2 MB, fragment-native (rope+prescale)
    __bf16* kfb = qfb + 1048576;         // 2 MB, fragment-native (rope, pi-permuted)
    __bf16* vfb = kfb + 1048576;         // 2 MB, fragment-native (PV operand order)
    __bf16* wb  = vfb + 1048576;         // 384 KB

    convert_w_kernel<<<192, 256, 0, stream>>>(Wq, Wk, Wv, wb);
    proj_kernel<<<512, 512, 0, stream>>>(x, wb, qfb, kfb, vfb);
    flash_kernel<<<256, 1024, 0, stream>>>(qfb, kfb, vfb, out);
}